// Round 2
// baseline (319.949 us; speedup 1.0000x reference)
//
#include <hip/hip_runtime.h>
#include <hip/hip_fp16.h>

#define DD 64
#define HC 384     // 2*D*L
#define SS 32
#define BINW 256   // nodes per bin (bin = dst >> 8); requires N < 65536
#define BSH 8
#define CAP 8192   // slab capacity per bin (avg load 4096 at E=800k)
#define CHUNK 2048 // edges per partition block

typedef _Float16 f16x8v __attribute__((ext_vector_type(8)));
typedef float f32x4v __attribute__((ext_vector_type(4)));

// ---------------- prep: bin_cur init + hcat zero + x->fp16 + W pack + BN fold --
// Wpk layout: idx = ((((layer*2+gemm)*4 + nt)*2 + kb)*64 + lane)*8 + j
//   value = W[layer][k = kb*32 + (lane>>4)*8 + j][c = nt*16 + (lane&15)]
// (A and B fragments use the same pi(g,j)=g*8+j k-permutation -> bijection, exact)
__global__ __launch_bounds__(256) void prep_kernel(
    const float* __restrict__ x, __half* __restrict__ hh0,
    int* __restrict__ bin_cur, float* __restrict__ hcat,
    const float* __restrict__ W1, const float* __restrict__ W2,
    const float* __restrict__ gma, const float* __restrict__ bta,
    const float* __restrict__ bnm, const float* __restrict__ bnv,
    const float* __restrict__ b1, __half* __restrict__ wpk,
    float* __restrict__ abbn, int nbins, int hcat4, int total)
{
  int gid = blockIdx.x * 256 + threadIdx.x;
  if (gid < nbins) bin_cur[gid] = gid * CAP;
  if (gid < hcat4) ((float4*)hcat)[gid] = make_float4(0.f, 0.f, 0.f, 0.f);
  if (gid < 3072) {                      // 3 layers * 2 gemms * 8 frag-blks * 64 lanes
    int lane_ = gid & 63;
    int rest = gid >> 6;                 // (((ly*2+gm)*4+nt)*2+kb) in 0..47
    int kb = rest & 1;
    int nt = (rest >> 1) & 3;
    int gm = (rest >> 3) & 1;
    int ly = rest >> 4;
    const float* W = gm ? W2 : W1;
    int c = nt * 16 + (lane_ & 15);
    int k0 = kb * 32 + (lane_ >> 4) * 8;
    f16x8v o;
    #pragma unroll
    for (int j = 0; j < 8; ++j)
      o[j] = (_Float16)W[((size_t)ly * DD + k0 + j) * DD + c];
    *(f16x8v*)(wpk + gid * 8) = o;
  }
  if (gid >= 4096 && gid < 4288) {       // fold BN: A*t + B
    int id = gid - 4096;
    int ly = id >> 6, c = id & 63;
    float A = gma[ly * DD + c] * rsqrtf(bnv[ly * DD + c] + 1e-5f);
    float B = fmaf(b1[ly * DD + c] - bnm[ly * DD + c], A, bta[ly * DD + c]);
    abbn[ly * 128 + c] = A;
    abbn[ly * 128 + 64 + c] = B;
  }
  int i = gid * 8;
  if (i < total) {
    float4 a = *(const float4*)(x + i);
    float4 b = *(const float4*)(x + i + 4);
    __half2 o[4];
    o[0] = __floats2half2_rn(a.x, a.y);
    o[1] = __floats2half2_rn(a.z, a.w);
    o[2] = __floats2half2_rn(b.x, b.y);
    o[3] = __floats2half2_rn(b.z, b.w);
    *(float4*)(hh0 + i) = *(float4*)o;
  }
}

// ---------------- partition edges into dst-bin slabs ----------------
__global__ __launch_bounds__(256) void bin_part_kernel(
    const int* __restrict__ ei, const float* __restrict__ ew,
    int* __restrict__ bin_cur, unsigned* __restrict__ pk_slab,
    unsigned short* __restrict__ dl_slab, int E)
{
  __shared__ unsigned spk[CHUNK];         // 8 KB
  __shared__ unsigned short sdst[CHUNK];  // 4 KB
  __shared__ int bcnt[256], boff[256], bcur[256], gbase[256], stmp[256];
  int t = threadIdx.x;
  int e0 = blockIdx.x * CHUNK;
  int m = min(CHUNK, E - e0);
  bcnt[t] = 0;
  __syncthreads();
  for (int i = t; i < m; i += 256)
    atomicAdd(&bcnt[ei[E + e0 + i] >> BSH], 1);
  __syncthreads();
  int v = bcnt[t];
  stmp[t] = v;
  __syncthreads();
  for (int o = 1; o < 256; o <<= 1) {
    int u = (t >= o) ? stmp[t - o] : 0;
    __syncthreads();
    stmp[t] += u;
    __syncthreads();
  }
  boff[t] = stmp[t] - v;
  bcur[t] = stmp[t] - v;
  if (v > 0) gbase[t] = atomicAdd(&bin_cur[t], v);
  __syncthreads();
  for (int i = t; i < m; i += 256) {
    unsigned d = (unsigned)ei[E + e0 + i];
    int b = d >> BSH;
    int p = atomicAdd(&bcur[b], 1);
    unsigned short wh = __half_as_ushort(__float2half(ew[e0 + i]));
    spk[p] = (unsigned)ei[e0 + i] | ((unsigned)wh << 16);
    sdst[p] = (unsigned short)d;
  }
  __syncthreads();
  for (int i = t; i < m; i += 256) {
    unsigned short d = sdst[i];
    int b = d >> BSH;
    int g = gbase[b] + (i - boff[b]);
    pk_slab[g] = spk[i];
    dl_slab[g] = d;
  }
}

// one block per bin: local hist + scan -> beg/end[], scatter 4-byte
// records into the bin's own slab window of packed[] (L2-resident)
__global__ __launch_bounds__(256) void fine_csr_kernel(
    const unsigned* __restrict__ pk_slab,
    const unsigned short* __restrict__ dl_slab,
    const int* __restrict__ bin_cur, int* __restrict__ beg,
    int* __restrict__ endo, unsigned* __restrict__ packed, int N)
{
  __shared__ int cnt[256], loff[256], cur[256], stmp[256];
  int t = threadIdx.x;
  int b = blockIdx.x;
  int sbase = b * CAP;
  int m = bin_cur[b] - sbase;
  cnt[t] = 0;
  __syncthreads();
  for (int i = t; i < m; i += 256)
    atomicAdd(&cnt[dl_slab[sbase + i] & 255], 1);
  __syncthreads();
  int v = cnt[t];
  stmp[t] = v;
  __syncthreads();
  for (int o = 1; o < 256; o <<= 1) {
    int u = (t >= o) ? stmp[t - o] : 0;
    __syncthreads();
    stmp[t] += u;
    __syncthreads();
  }
  loff[t] = stmp[t] - v;
  cur[t] = loff[t];
  int node = b * BINW + t;
  if (node < N) {
    beg[node] = sbase + loff[t];
    endo[node] = sbase + loff[t] + v;
  }
  __syncthreads();
  for (int i = t; i < m; i += 256) {
    int dl = dl_slab[sbase + i] & 255;
    int p = atomicAdd(&cur[dl], 1);
    packed[sbase + p] = pk_slab[sbase + i];
  }
}

// ---------------- fused layer: gather -> LDS z -> MFMA MLP -> pooling ----------
// Block = 256 threads = 64 nodes. Phase 1: wave w gathers its 16 nodes, 4 at a
// time (4 independent edge chains per lane for MLP), 8 edge-subgroups x 8 lanes,
// lane holds 8 channels. z written fp16 directly into LDS in the GEMM1-A
// XOR-swizzled layout (upper 8 KB of tileF; dead before epilogue2 clobbers it).
// Phase 2: 16x16x32 MFMA MLP (same as previous node_mfma kernel).
// C/D layout: col=lane&15, row=(lane>>4)*4+reg (guide-verified, m89).
__global__ __launch_bounds__(256) void layer_kernel(
    const __half* __restrict__ hh, const unsigned* __restrict__ packed,
    const int* __restrict__ begA, const int* __restrict__ endA,
    const float* __restrict__ epsv, __half* __restrict__ hhout,
    const __half* __restrict__ wpk, const float* __restrict__ abbn,
    const float* __restrict__ b2, const float* __restrict__ pmask,
    const int* __restrict__ batch, float* __restrict__ hcat,
    int layer, int N)
{
  __shared__ float tileF[DD * DD];       // 16 KB, reused across phases
  __half* tileH = (__half*)tileF;        // fp16 alias, bytes 0..8191
  __half* zT = ((__half*)tileF) + 4096;  // z tile fp16, bytes 8192..16383
  const int wave = threadIdx.x >> 6;
  const int lane = threadIdx.x & 63;
  const int sub = lane >> 3;             // 0..7 edge-subgroup
  const int q8 = lane & 7;               // channel-block for gather
  const int ch0 = q8 * 8;
  const int n0 = blockIdx.x * 64;
  const float e1 = 1.0f + epsv[layer];

  // ---- phase 1: gather 16 nodes per wave, 4 chains at a time ----
  for (int p = 0; p < 4; ++p) {
    int nbase = n0 + wave * 16 + p * 4;
    float acc[4][8];
    int e[4], en[4];
    #pragma unroll
    for (int c = 0; c < 4; ++c) {
      int n = nbase + c;
      bool valid = n < N;
      e[c] = valid ? begA[n] + sub : 0;
      en[c] = valid ? endA[n] : 0;
      #pragma unroll
      for (int j = 0; j < 8; ++j) acc[c][j] = 0.f;
    }
    while (e[0] < en[0] || e[1] < en[1] || e[2] < en[2] || e[3] < en[3]) {
      #pragma unroll
      for (int c = 0; c < 4; ++c) {
        if (e[c] < en[c]) {
          unsigned pk = packed[e[c]];
          float4 r = *(const float4*)(hh + (size_t)(pk & 0xffffu) * DD + ch0);
          float w = __half2float(__ushort_as_half((unsigned short)(pk >> 16)));
          const __half2* H = (const __half2*)&r;
          #pragma unroll
          for (int j = 0; j < 4; ++j) {
            float2 f = __half22float2(H[j]);
            acc[c][2 * j]     = fmaf(w, f.x, acc[c][2 * j]);
            acc[c][2 * j + 1] = fmaf(w, f.y, acc[c][2 * j + 1]);
          }
        }
        e[c] += 8;
      }
    }
    #pragma unroll
    for (int c = 0; c < 4; ++c)
      #pragma unroll
      for (int j = 0; j < 8; ++j) {
        acc[c][j] += __shfl_xor(acc[c][j], 8);
        acc[c][j] += __shfl_xor(acc[c][j], 16);
        acc[c][j] += __shfl_xor(acc[c][j], 32);
      }
    if (sub == 0) {
      #pragma unroll
      for (int c = 0; c < 4; ++c) {
        int n = nbase + c;
        int row = n - n0;
        f16x8v qv;
        if (n < N) {
          float4 sr = *(const float4*)(hh + (size_t)n * DD + ch0);
          const __half2* S = (const __half2*)&sr;
          #pragma unroll
          for (int j = 0; j < 4; ++j) {
            float2 f = __half22float2(S[j]);
            qv[2 * j]     = (_Float16)fmaf(e1, f.x, acc[c][2 * j]);
            qv[2 * j + 1] = (_Float16)fmaf(e1, f.y, acc[c][2 * j + 1]);
          }
        } else {
          #pragma unroll
          for (int j = 0; j < 8; ++j) qv[j] = (_Float16)0.f;
        }
        *(f16x8v*)(zT + row * DD + ((q8 ^ (row & 7)) * 8)) = qv;
      }
    }
  }
  __syncthreads();

  // ---- phase 2: MFMA MLP ----
  const int g = lane >> 4;               // k-group
  const int cr = lane & 15;              // A-row / D-col within tile
  const int arow = wave * 16 + cr;       // (arow & 7) == (cr & 7)
  const __half* wl  = wpk + (size_t)layer * 8192;  // gemm1 pack
  const __half* w2l = wl + 4096;                   // gemm2 pack

  // GEMM1: z @ W1, A from swizzled zT
  f16x8v a0 = *(const f16x8v*)(zT + arow * DD + ((g ^ (cr & 7)) * 8));
  f16x8v a1 = *(const f16x8v*)(zT + arow * DD + (((g + 4) ^ (cr & 7)) * 8));
  f32x4v acc1[4];
  #pragma unroll
  for (int nt = 0; nt < 4; ++nt) {
    f16x8v b0 = *(const f16x8v*)(wl + (nt * 2 + 0) * 512 + lane * 8);
    f16x8v b1 = *(const f16x8v*)(wl + (nt * 2 + 1) * 512 + lane * 8);
    acc1[nt] = (f32x4v){0.f, 0.f, 0.f, 0.f};
    acc1[nt] = __builtin_amdgcn_mfma_f32_16x16x32_f16(a0, b0, acc1[nt], 0, 0, 0);
    acc1[nt] = __builtin_amdgcn_mfma_f32_16x16x32_f16(a1, b1, acc1[nt], 0, 0, 0);
  }
  // epilogue1: BN(fold A,B) + ReLU -> fp16 LDS (XOR-swizzled, bytes 0..8191)
  #pragma unroll
  for (int nt = 0; nt < 4; ++nt) {
    int c = nt * 16 + cr;
    float Ab = abbn[layer * 128 + c];
    float Bb = abbn[layer * 128 + 64 + c];
    #pragma unroll
    for (int r = 0; r < 4; ++r) {
      int row = wave * 16 + g * 4 + r;
      float v = fmaxf(fmaf(acc1[nt][r], Ab, Bb), 0.f);
      tileH[row * DD + (((c >> 3) ^ (row & 7)) * 8) + (c & 7)] = __float2half(v);
    }
  }
  __syncthreads();
  // GEMM2: act @ W2
  f16x8v a20 = *(const f16x8v*)(tileH + arow * DD + ((g ^ (arow & 7)) * 8));
  f16x8v a21 = *(const f16x8v*)(tileH + arow * DD + (((4 + g) ^ (arow & 7)) * 8));
  f32x4v acc2[4];
  #pragma unroll
  for (int nt = 0; nt < 4; ++nt) {
    f16x8v b0 = *(const f16x8v*)(w2l + (nt * 2 + 0) * 512 + lane * 8);
    f16x8v b1 = *(const f16x8v*)(w2l + (nt * 2 + 1) * 512 + lane * 8);
    acc2[nt] = (f32x4v){0.f, 0.f, 0.f, 0.f};
    acc2[nt] = __builtin_amdgcn_mfma_f32_16x16x32_f16(a20, b0, acc2[nt], 0, 0, 0);
    acc2[nt] = __builtin_amdgcn_mfma_f32_16x16x32_f16(a21, b1, acc2[nt], 0, 0, 0);
  }
  __syncthreads();   // all A2 LDS reads done before tileF overwrite
  // epilogue2: +b2, ReLU -> fp32 LDS (rotate-skewed; clobbers zT, now dead)
  #pragma unroll
  for (int nt = 0; nt < 4; ++nt) {
    int c = nt * 16 + cr;
    float bb = b2[layer * DD + c];
    #pragma unroll
    for (int r = 0; r < 4; ++r) {
      int row = wave * 16 + g * 4 + r;
      tileF[row * DD + ((c + row) & 63)] = fmaxf(acc2[nt][r] + bb, 0.f);
    }
  }
  __syncthreads();
  // copy-out h fp16, coalesced (8 threads per 128B row)
  #pragma unroll
  for (int i = 0; i < 2; ++i) {
    int id = i * 256 + threadIdx.x;
    int rw = id >> 3, q = id & 7;
    if (n0 + rw < N) {
      f16x8v hv;
      #pragma unroll
      for (int j = 0; j < 8; ++j)
        hv[j] = (_Float16)tileF[rw * DD + ((q * 8 + j + rw) & 63)];
      *(f16x8v*)(hhout + (size_t)(n0 + rw) * DD + q * 8) = hv;
    }
  }
  // pooling (fp32-exact): wave w owns rows w*16..+15, lane = channel
  float accp = 0.0f;
  int gcur = -1;
  for (int i = 0; i < 16; ++i) {
    int r = wave * 16 + i;
    int n = n0 + r;
    if (n >= N) break;
    float v = tileF[r * DD + ((lane + r) & 63)];
    int gb = batch[n];                   // wave-uniform -> s_load
    if (gb != gcur) {
      if (gcur >= 0) atomicAdd(&hcat[gcur * HC + layer * 128 + lane], accp);
      gcur = gb; accp = 0.0f;
    }
    accp = fmaf(v, pmask[n], accp);
  }
  if (gcur >= 0) atomicAdd(&hcat[gcur * HC + layer * 128 + lane], accp);
}

// ---------------- final linear (+ fp16 center gather fused) ----------------
__global__ __launch_bounds__(256) void final_kernel(
    const float* __restrict__ hcat, const __half* __restrict__ h1,
    const __half* __restrict__ h2, const __half* __restrict__ h3,
    const int* __restrict__ mapping, const float* __restrict__ lw,
    const float* __restrict__ lb, float* __restrict__ out, int G)
{
  int gid = blockIdx.x * 256 + threadIdx.x;
  int g = gid >> 5, s = gid & 31;
  if (g >= G) return;
  float acc = lb[s];
  size_t mrow = (size_t)mapping[g] * DD;
  #pragma unroll
  for (int l = 0; l < 3; ++l) {
    const float* hc = hcat + g * HC + l * 128;
    const float* lwa = lw + (l * 128) * SS + s;
    #pragma unroll 4
    for (int c = 0; c < 64; ++c)
      acc = fmaf(hc[c], lwa[c * SS], acc);
    const __half* hr = ((l == 0) ? h1 : ((l == 1) ? h2 : h3)) + mrow;
    const float* lwc = lw + (l * 128 + 64) * SS + s;
    #pragma unroll 4
    for (int c = 0; c < 64; ++c)
      acc = fmaf(__half2float(hr[c]), lwc[c * SS], acc);
  }
  out[g * SS + s] = acc;
}

extern "C" void kernel_launch(void* const* d_in, const int* in_sizes, int n_in,
                              void* d_out, int out_size, void* d_ws, size_t ws_size,
                              hipStream_t stream)
{
  const float* x     = (const float*)d_in[0];
  const float* ew    = (const float*)d_in[1];
  const float* pmask = (const float*)d_in[2];
  const float* W1    = (const float*)d_in[3];
  const float* b1    = (const float*)d_in[4];
  const float* gma   = (const float*)d_in[5];
  const float* bta   = (const float*)d_in[6];
  const float* bnm   = (const float*)d_in[7];
  const float* bnv   = (const float*)d_in[8];
  const float* W2    = (const float*)d_in[9];
  const float* b2    = (const float*)d_in[10];
  const float* epsv  = (const float*)d_in[11];
  const float* lw    = (const float*)d_in[12];
  const float* lb    = (const float*)d_in[13];
  const int*   ei    = (const int*)d_in[14];
  const int*   batch = (const int*)d_in[15];
  const int*   mapping = (const int*)d_in[16];

  const int N = in_sizes[2];     // 50000 (< 65536 required for packing)
  const int E = in_sizes[1];
  const int G = in_sizes[16];
  const int nbins = (N + BINW - 1) / BINW;   // 196 <= 256
  const int nchunks = (E + CHUNK - 1) / CHUNK;

  __half*   hh0  = (__half*)d_ws;                     // N*DD fp16
  __half*   hh1  = hh0 + (size_t)N * DD;              // N*DD
  __half*   hh2  = hh1 + (size_t)N * DD;              // N*DD
  __half*   hh3  = hh2 + (size_t)N * DD;              // N*DD
  float*    hcat = (float*)(hh3 + (size_t)N * DD);    // G*HC
  int*      beg  = (int*)(hcat + (size_t)G * HC);     // N
  int*      endo = beg + N;                           // N
  int*      bin_cur = endo + N;                       // nbins (+pad)
  unsigned* packed  = (unsigned*)(bin_cur + 256);     // nbins*CAP
  unsigned* pk_slab = packed + (size_t)nbins * CAP;   // nbins*CAP
  unsigned short* dl_slab =
      (unsigned short*)(pk_slab + (size_t)nbins * CAP); // nbins*CAP
  __half*   wpk  = (__half*)(dl_slab + (size_t)nbins * CAP); // 24576 halves
  float*    abbn = (float*)(wpk + 24576);             // 384 floats
  float* fout = (float*)d_out;

  // ---- prep (bin_cur init + hcat zero + x->fp16 + W pack + BN fold) ----
  prep_kernel<<<(N * DD / 8 + 255) / 256, 256, 0, stream>>>(
      x, hh0, bin_cur, hcat, W1, W2, gma, bta, bnm, bnv, b1,
      wpk, abbn, nbins, G * HC / 4, N * DD);

  // ---- slab-binned CSR build (2 dispatches) ----
  bin_part_kernel<<<nchunks, 256, 0, stream>>>(ei, ew, bin_cur,
                                               pk_slab, dl_slab, E);
  fine_csr_kernel<<<nbins, 256, 0, stream>>>(pk_slab, dl_slab, bin_cur,
                                             beg, endo, packed, N);

  // ---- 3 fused GIN layers (gather + MLP + pooling in one dispatch) ----
  __half* hhs[4] = {hh0, hh1, hh2, hh3};
  for (int layer = 0; layer < 3; ++layer) {
    layer_kernel<<<(N + 63) / 64, 256, 0, stream>>>(
        hhs[layer], packed, beg, endo, epsv, hhs[layer + 1],
        wpk, abbn, b2, pmask, batch, hcat, layer, N);
  }
  final_kernel<<<(G * SS + 255) / 256, 256, 0, stream>>>(
      hcat, hh1, hh2, hh3, mapping, lw, lb, fout, G);
}

// Round 3
// 255.946 us; speedup vs baseline: 1.2501x; 1.2501x over previous
//
#include <hip/hip_runtime.h>
#include <hip/hip_fp16.h>

#define DD 64
#define HC 384     // 2*D*L
#define SS 32
#define BINW 256   // nodes per bin (bin = dst >> 8); requires N < 65536
#define BSH 8
#define CAP 8192   // slab capacity per bin (avg load 4096 at E=800k)
#define CHUNK 2048 // edges per partition block

typedef _Float16 f16x8v __attribute__((ext_vector_type(8)));
typedef float f32x4v __attribute__((ext_vector_type(4)));

// ---------------- merged front-end: bin_part (blocks < nchunks) + prep ----------
// bin_cur is zero-initialized by hipMemsetAsync; slab offsets are relative.
// Wpk layout: idx = ((((layer*2+gemm)*4 + nt)*2 + kb)*64 + lane)*8 + j
//   value = W[layer][k = kb*32 + (lane>>4)*8 + j][c = nt*16 + (lane&15)]
// (A and B fragments use the same pi(g,j)=g*8+j k-permutation -> bijection, exact)
__global__ __launch_bounds__(256) void front_kernel(
    const int* __restrict__ ei, const float* __restrict__ ew,
    int* __restrict__ bin_cur, unsigned* __restrict__ pk_slab,
    unsigned short* __restrict__ dl_slab, int E, int nchunks,
    const float* __restrict__ x, __half* __restrict__ hh0,
    const float* __restrict__ W1, const float* __restrict__ W2,
    const float* __restrict__ gma, const float* __restrict__ bta,
    const float* __restrict__ bnm, const float* __restrict__ bnv,
    const float* __restrict__ b1, __half* __restrict__ wpk,
    float* __restrict__ abbn, int total)
{
  __shared__ unsigned spk[CHUNK];         // 8 KB
  __shared__ unsigned short sdst[CHUNK];  // 4 KB
  __shared__ int bcnt[256], boff[256], bcur[256], gbase[256], stmp[256];
  int t = threadIdx.x;

  if ((int)blockIdx.x >= nchunks) {
    // ---------------- prep part ----------------
    int gid = (blockIdx.x - nchunks) * 256 + t;
    if (gid < 3072) {                    // 3 layers * 2 gemms * 8 frag-blks * 64 lanes
      int lane_ = gid & 63;
      int rest = gid >> 6;               // (((ly*2+gm)*4+nt)*2+kb) in 0..47
      int kb = rest & 1;
      int nt = (rest >> 1) & 3;
      int gm = (rest >> 3) & 1;
      int ly = rest >> 4;
      const float* W = gm ? W2 : W1;
      int c = nt * 16 + (lane_ & 15);
      int k0 = kb * 32 + (lane_ >> 4) * 8;
      f16x8v o;
      #pragma unroll
      for (int j = 0; j < 8; ++j)
        o[j] = (_Float16)W[((size_t)ly * DD + k0 + j) * DD + c];
      *(f16x8v*)(wpk + gid * 8) = o;
    }
    if (gid >= 4096 && gid < 4288) {     // fold BN: A*t + B
      int id = gid - 4096;
      int ly = id >> 6, c = id & 63;
      float A = gma[ly * DD + c] * rsqrtf(bnv[ly * DD + c] + 1e-5f);
      float B = fmaf(b1[ly * DD + c] - bnm[ly * DD + c], A, bta[ly * DD + c]);
      abbn[ly * 128 + c] = A;
      abbn[ly * 128 + 64 + c] = B;
    }
    int i = gid * 8;
    if (i < total) {
      float4 a = *(const float4*)(x + i);
      float4 b = *(const float4*)(x + i + 4);
      __half2 o[4];
      o[0] = __floats2half2_rn(a.x, a.y);
      o[1] = __floats2half2_rn(a.z, a.w);
      o[2] = __floats2half2_rn(b.x, b.y);
      o[3] = __floats2half2_rn(b.z, b.w);
      *(float4*)(hh0 + i) = *(float4*)o;
    }
    return;
  }

  // ---------------- bin_part: partition edges into dst-bin slabs ----------------
  int e0 = blockIdx.x * CHUNK;
  int m = min(CHUNK, E - e0);
  bcnt[t] = 0;
  __syncthreads();
  for (int i = t; i < m; i += 256)
    atomicAdd(&bcnt[ei[E + e0 + i] >> BSH], 1);
  __syncthreads();
  int v = bcnt[t];
  stmp[t] = v;
  __syncthreads();
  for (int o = 1; o < 256; o <<= 1) {
    int u = (t >= o) ? stmp[t - o] : 0;
    __syncthreads();
    stmp[t] += u;
    __syncthreads();
  }
  boff[t] = stmp[t] - v;
  bcur[t] = stmp[t] - v;
  if (v > 0) gbase[t] = atomicAdd(&bin_cur[t], v);   // relative (zero-based)
  __syncthreads();
  for (int i = t; i < m; i += 256) {
    unsigned d = (unsigned)ei[E + e0 + i];
    int b = d >> BSH;
    int p = atomicAdd(&bcur[b], 1);
    unsigned short wh = __half_as_ushort(__float2half(ew[e0 + i]));
    spk[p] = (unsigned)ei[e0 + i] | ((unsigned)wh << 16);
    sdst[p] = (unsigned short)d;
  }
  __syncthreads();
  for (int i = t; i < m; i += 256) {
    unsigned short d = sdst[i];
    int b = d >> BSH;
    int g = b * CAP + gbase[b] + (i - boff[b]);
    pk_slab[g] = spk[i];
    dl_slab[g] = d;
  }
}

// one block per bin: local hist + scan -> beg/end[], scatter 4-byte
// records into the bin's own slab window of packed[] (L2-resident)
__global__ __launch_bounds__(256) void fine_csr_kernel(
    const unsigned* __restrict__ pk_slab,
    const unsigned short* __restrict__ dl_slab,
    const int* __restrict__ bin_cur, int* __restrict__ beg,
    int* __restrict__ endo, unsigned* __restrict__ packed, int N)
{
  __shared__ int cnt[256], loff[256], cur[256], stmp[256];
  int t = threadIdx.x;
  int b = blockIdx.x;
  int sbase = b * CAP;
  int m = bin_cur[b];                    // relative count
  cnt[t] = 0;
  __syncthreads();
  for (int i = t; i < m; i += 256)
    atomicAdd(&cnt[dl_slab[sbase + i] & 255], 1);
  __syncthreads();
  int v = cnt[t];
  stmp[t] = v;
  __syncthreads();
  for (int o = 1; o < 256; o <<= 1) {
    int u = (t >= o) ? stmp[t - o] : 0;
    __syncthreads();
    stmp[t] += u;
    __syncthreads();
  }
  loff[t] = stmp[t] - v;
  cur[t] = loff[t];
  int node = b * BINW + t;
  if (node < N) {
    beg[node] = sbase + loff[t];
    endo[node] = sbase + loff[t] + v;
  }
  __syncthreads();
  for (int i = t; i < m; i += 256) {
    int dl = dl_slab[sbase + i] & 255;
    int p = atomicAdd(&cur[dl], 1);
    packed[sbase + p] = pk_slab[sbase + i];
  }
}

// ---------------- gather + z: TWO nodes per wave; z written fp16 ----------------
// 8 edge-subgroups x 8 lanes; lane holds 8 channels (16 B fp16 row).
// Two independent edge-list chains per lane hide L2-miss latency.
__global__ __launch_bounds__(256) void gather_kernel(
    const __half* __restrict__ hh, const unsigned* __restrict__ packed,
    const int* __restrict__ begA, const int* __restrict__ endA,
    const float* __restrict__ epsv, __half* __restrict__ zh, int layer, int N)
{
  int wave = threadIdx.x >> 6;
  int lane = threadIdx.x & 63;
  int sub = lane >> 3;          // 0..7
  int ch0 = (lane & 7) * 8;     // 8 channels per lane
  int na = blockIdx.x * 8 + wave * 2;
  int nb = na + 1;
  if (na >= N) return;
  bool hasB = nb < N;
  int bega = begA[na], enda = endA[na];
  int begb = hasB ? begA[nb] : 0, endb = hasB ? endA[nb] : 0;
  float accA[8] = {0, 0, 0, 0, 0, 0, 0, 0};
  float accB[8] = {0, 0, 0, 0, 0, 0, 0, 0};
  int ea = bega + sub, eb = begb + sub;
  while (ea < enda || eb < endb) {
    bool va = ea < enda;
    bool vb = eb < endb;
    unsigned pa = 0, pb = 0;
    if (va) pa = packed[ea];
    if (vb) pb = packed[eb];
    float4 ra, rb;
    if (va) ra = *(const float4*)(hh + (size_t)(pa & 0xffffu) * DD + ch0);
    if (vb) rb = *(const float4*)(hh + (size_t)(pb & 0xffffu) * DD + ch0);
    if (va) {
      float w = __half2float(__ushort_as_half((unsigned short)(pa >> 16)));
      const __half2* H = (const __half2*)&ra;
      #pragma unroll
      for (int j = 0; j < 4; ++j) {
        float2 f = __half22float2(H[j]);
        accA[2 * j]     = fmaf(w, f.x, accA[2 * j]);
        accA[2 * j + 1] = fmaf(w, f.y, accA[2 * j + 1]);
      }
    }
    if (vb) {
      float w = __half2float(__ushort_as_half((unsigned short)(pb >> 16)));
      const __half2* H = (const __half2*)&rb;
      #pragma unroll
      for (int j = 0; j < 4; ++j) {
        float2 f = __half22float2(H[j]);
        accB[2 * j]     = fmaf(w, f.x, accB[2 * j]);
        accB[2 * j + 1] = fmaf(w, f.y, accB[2 * j + 1]);
      }
    }
    ea += 8; eb += 8;
  }
  #pragma unroll
  for (int j = 0; j < 8; ++j) {
    accA[j] += __shfl_xor(accA[j], 8);
    accA[j] += __shfl_xor(accA[j], 16);
    accA[j] += __shfl_xor(accA[j], 32);
    accB[j] += __shfl_xor(accB[j], 8);
    accB[j] += __shfl_xor(accB[j], 16);
    accB[j] += __shfl_xor(accB[j], 32);
  }
  if (sub == 0) {
    float e1 = 1.0f + epsv[layer];
    {
      float4 sr = *(const float4*)(hh + (size_t)na * DD + ch0);
      const __half2* S = (const __half2*)&sr;
      f16x8v q;
      #pragma unroll
      for (int j = 0; j < 4; ++j) {
        float2 f = __half22float2(S[j]);
        q[2 * j]     = (_Float16)fmaf(e1, f.x, accA[2 * j]);
        q[2 * j + 1] = (_Float16)fmaf(e1, f.y, accA[2 * j + 1]);
      }
      *(f16x8v*)(zh + (size_t)na * DD + ch0) = q;
    }
    if (hasB) {
      float4 sr = *(const float4*)(hh + (size_t)nb * DD + ch0);
      const __half2* S = (const __half2*)&sr;
      f16x8v q;
      #pragma unroll
      for (int j = 0; j < 4; ++j) {
        float2 f = __half22float2(S[j]);
        q[2 * j]     = (_Float16)fmaf(e1, f.x, accB[2 * j]);
        q[2 * j + 1] = (_Float16)fmaf(e1, f.y, accB[2 * j + 1]);
      }
      *(f16x8v*)(zh + (size_t)nb * DD + ch0) = q;
    }
  }
}

// ---------------- per-node GIN MLP via MFMA + pooling ----------------
// Block = 256 (4 waves) = 64 nodes. Wave w owns the 16-row m-tile w.
// GEMM1: A-frags straight from global fp16 z (row-major, 16B/lane),
//        B-frags from prepacked W (pi(g,j)=g*8+j on both sides -> exact).
// Transpose GEMM1->GEMM2 through fp16 LDS tile, XOR-swizzled 16B blocks
// (2-way bank reads = free). Final h kept fp32 in LDS for exact pooling.
// C/D layout: col=lane&15, row=(lane>>4)*4+reg (guide-verified, m89).
__global__ __launch_bounds__(256) void node_mfma_kernel(
    const __half* __restrict__ zh, __half* __restrict__ hhout,
    const __half* __restrict__ wpk, const float* __restrict__ abbn,
    const float* __restrict__ b2, const float* __restrict__ pmask,
    const int* __restrict__ batch, float* __restrict__ hcat,
    int layer, int N)
{
  __shared__ float tileF[DD * DD];       // 16 KB, reused across phases
  __half* tileH = (__half*)tileF;        // fp16 alias (first 8 KB)
  const int wave = threadIdx.x >> 6;
  const int lane = threadIdx.x & 63;
  const int g = lane >> 4;               // k-group
  const int cr = lane & 15;              // A-row / D-col within tile
  const int n0 = blockIdx.x * 64;
  const int mrow = n0 + wave * 16 + cr;  // node row for A fragments

  const __half* wl  = wpk + (size_t)layer * 8192;  // gemm1 pack
  const __half* w2l = wl + 4096;                   // gemm2 pack

  // ---- GEMM1: z @ W1 ----
  f16x8v a0 = *(const f16x8v*)(zh + (size_t)mrow * DD + g * 8);
  f16x8v a1 = *(const f16x8v*)(zh + (size_t)mrow * DD + 32 + g * 8);
  f32x4v acc[4];
  #pragma unroll
  for (int nt = 0; nt < 4; ++nt) {
    f16x8v b0 = *(const f16x8v*)(wl + (nt * 2 + 0) * 512 + lane * 8);
    f16x8v b1 = *(const f16x8v*)(wl + (nt * 2 + 1) * 512 + lane * 8);
    acc[nt] = (f32x4v){0.f, 0.f, 0.f, 0.f};
    acc[nt] = __builtin_amdgcn_mfma_f32_16x16x32_f16(a0, b0, acc[nt], 0, 0, 0);
    acc[nt] = __builtin_amdgcn_mfma_f32_16x16x32_f16(a1, b1, acc[nt], 0, 0, 0);
  }
  // ---- epilogue1: BN(fold A,B) + ReLU -> fp16 LDS (XOR-swizzled) ----
  #pragma unroll
  for (int nt = 0; nt < 4; ++nt) {
    int c = nt * 16 + cr;
    float Ab = abbn[layer * 128 + c];
    float Bb = abbn[layer * 128 + 64 + c];
    #pragma unroll
    for (int r = 0; r < 4; ++r) {
      int row = wave * 16 + g * 4 + r;
      float v = fmaxf(fmaf(acc[nt][r], Ab, Bb), 0.f);
      tileH[row * DD + (((c >> 3) ^ (row & 7)) * 8) + (c & 7)] = __float2half(v);
    }
  }
  __syncthreads();
  // ---- GEMM2: act @ W2 ----
  const int arow = wave * 16 + cr;
  f16x8v a20 = *(const f16x8v*)(tileH + arow * DD + ((g ^ (arow & 7)) * 8));
  f16x8v a21 = *(const f16x8v*)(tileH + arow * DD + (((4 + g) ^ (arow & 7)) * 8));
  f32x4v acc2[4];
  #pragma unroll
  for (int nt = 0; nt < 4; ++nt) {
    f16x8v b0 = *(const f16x8v*)(w2l + (nt * 2 + 0) * 512 + lane * 8);
    f16x8v b1 = *(const f16x8v*)(w2l + (nt * 2 + 1) * 512 + lane * 8);
    acc2[nt] = (f32x4v){0.f, 0.f, 0.f, 0.f};
    acc2[nt] = __builtin_amdgcn_mfma_f32_16x16x32_f16(a20, b0, acc2[nt], 0, 0, 0);
    acc2[nt] = __builtin_amdgcn_mfma_f32_16x16x32_f16(a21, b1, acc2[nt], 0, 0, 0);
  }
  __syncthreads();   // all A2 LDS reads done before tileF overwrite
  // ---- epilogue2: +b2, ReLU -> fp32 LDS (rotate-skewed) ----
  #pragma unroll
  for (int nt = 0; nt < 4; ++nt) {
    int c = nt * 16 + cr;
    float bb = b2[layer * DD + c];
    #pragma unroll
    for (int r = 0; r < 4; ++r) {
      int row = wave * 16 + g * 4 + r;
      tileF[row * DD + ((c + row) & 63)] = fmaxf(acc2[nt][r] + bb, 0.f);
    }
  }
  __syncthreads();
  // ---- copy-out h fp16, coalesced (8 threads per 128B row) ----
  #pragma unroll
  for (int i = 0; i < 2; ++i) {
    int id = i * 256 + threadIdx.x;
    int rw = id >> 3, q = id & 7;
    if (n0 + rw < N) {
      f16x8v hv;
      #pragma unroll
      for (int j = 0; j < 8; ++j)
        hv[j] = (_Float16)tileF[rw * DD + ((q * 8 + j + rw) & 63)];
      *(f16x8v*)(hhout + (size_t)(n0 + rw) * DD + q * 8) = hv;
    }
  }
  // ---- pooling (fp32-exact): wave w owns rows w*16..+15, lane = channel ----
  float accp = 0.0f;
  int gcur = -1;
  for (int i = 0; i < 16; ++i) {
    int r = wave * 16 + i;
    int n = n0 + r;
    if (n >= N) break;
    float v = tileF[r * DD + ((lane + r) & 63)];
    int gb = batch[n];                   // wave-uniform -> s_load
    if (gb != gcur) {
      if (gcur >= 0) atomicAdd(&hcat[gcur * HC + layer * 128 + lane], accp);
      gcur = gb; accp = 0.0f;
    }
    accp = fmaf(v, pmask[n], accp);
  }
  if (gcur >= 0) atomicAdd(&hcat[gcur * HC + layer * 128 + lane], accp);
}

// ---------------- final linear (+ fp16 center gather fused) ----------------
__global__ __launch_bounds__(256) void final_kernel(
    const float* __restrict__ hcat, const __half* __restrict__ h1,
    const __half* __restrict__ h2, const __half* __restrict__ h3,
    const int* __restrict__ mapping, const float* __restrict__ lw,
    const float* __restrict__ lb, float* __restrict__ out, int G)
{
  int gid = blockIdx.x * 256 + threadIdx.x;
  int g = gid >> 5, s = gid & 31;
  if (g >= G) return;
  float acc = lb[s];
  size_t mrow = (size_t)mapping[g] * DD;
  #pragma unroll
  for (int l = 0; l < 3; ++l) {
    const float* hc = hcat + g * HC + l * 128;
    const float* lwa = lw + (l * 128) * SS + s;
    #pragma unroll 4
    for (int c = 0; c < 64; ++c)
      acc = fmaf(hc[c], lwa[c * SS], acc);
    const __half* hr = ((l == 0) ? h1 : ((l == 1) ? h2 : h3)) + mrow;
    const float* lwc = lw + (l * 128 + 64) * SS + s;
    #pragma unroll 4
    for (int c = 0; c < 64; ++c)
      acc = fmaf(__half2float(hr[c]), lwc[c * SS], acc);
  }
  out[g * SS + s] = acc;
}

extern "C" void kernel_launch(void* const* d_in, const int* in_sizes, int n_in,
                              void* d_out, int out_size, void* d_ws, size_t ws_size,
                              hipStream_t stream)
{
  const float* x     = (const float*)d_in[0];
  const float* ew    = (const float*)d_in[1];
  const float* pmask = (const float*)d_in[2];
  const float* W1    = (const float*)d_in[3];
  const float* b1    = (const float*)d_in[4];
  const float* gma   = (const float*)d_in[5];
  const float* bta   = (const float*)d_in[6];
  const float* bnm   = (const float*)d_in[7];
  const float* bnv   = (const float*)d_in[8];
  const float* W2    = (const float*)d_in[9];
  const float* b2    = (const float*)d_in[10];
  const float* epsv  = (const float*)d_in[11];
  const float* lw    = (const float*)d_in[12];
  const float* lb    = (const float*)d_in[13];
  const int*   ei    = (const int*)d_in[14];
  const int*   batch = (const int*)d_in[15];
  const int*   mapping = (const int*)d_in[16];

  const int N = in_sizes[2];     // 50000 (< 65536 required for packing)
  const int E = in_sizes[1];
  const int G = in_sizes[16];
  const int nbins = (N + BINW - 1) / BINW;   // 196 <= 256
  const int nchunks = (E + CHUNK - 1) / CHUNK;
  const int prepb = (N * DD / 8 + 255) / 256;

  __half*   hh0  = (__half*)d_ws;                     // N*DD fp16
  __half*   hh1  = hh0 + (size_t)N * DD;              // N*DD
  __half*   hh2  = hh1 + (size_t)N * DD;              // N*DD
  __half*   hh3  = hh2 + (size_t)N * DD;              // N*DD
  __half*   zh   = hh3 + (size_t)N * DD;              // N*DD fp16 z scratch
  float*    hcat = (float*)(zh + (size_t)N * DD);     // G*HC      <-- memset 0
  int*      beg  = (int*)(hcat + (size_t)G * HC);     // N
  int*      endo = beg + N;                           // N
  int*      bin_cur = endo + N;                       // 256       <-- memset 0
  unsigned* packed  = (unsigned*)(bin_cur + 256);     // nbins*CAP
  unsigned* pk_slab = packed + (size_t)nbins * CAP;   // nbins*CAP
  unsigned short* dl_slab =
      (unsigned short*)(pk_slab + (size_t)nbins * CAP); // nbins*CAP
  __half*   wpk  = (__half*)(dl_slab + (size_t)nbins * CAP); // 24576 halves
  float*    abbn = (float*)(wpk + 24576);             // 384 floats
  float* fout = (float*)d_out;

  // ---- one memset covers hcat..bin_cur (beg/endo overwritten later anyway) ----
  size_t zero_bytes = (size_t)G * HC * 4 + (size_t)N * 4 * 2 + 256 * 4;
  hipMemsetAsync(hcat, 0, zero_bytes, stream);

  // ---- merged front-end: edge binning + (x->fp16, W pack, BN fold) ----
  front_kernel<<<nchunks + prepb, 256, 0, stream>>>(
      ei, ew, bin_cur, pk_slab, dl_slab, E, nchunks,
      x, hh0, W1, W2, gma, bta, bnm, bnv, b1, wpk, abbn, N * DD);

  fine_csr_kernel<<<nbins, 256, 0, stream>>>(pk_slab, dl_slab, bin_cur,
                                             beg, endo, packed, N);

  // ---- 3 GIN layers ----
  __half* hhs[4] = {hh0, hh1, hh2, hh3};
  for (int layer = 0; layer < 3; ++layer) {
    gather_kernel<<<(N + 7) / 8, 256, 0, stream>>>(
        hhs[layer], packed, beg, endo, epsv, zh, layer, N);
    node_mfma_kernel<<<(N + 63) / 64, 256, 0, stream>>>(
        zh, hhs[layer + 1], wpk, abbn, b2, pmask, batch, hcat, layer, N);
  }
  final_kernel<<<(G * SS + 255) / 256, 256, 0, stream>>>(
      hcat, hh1, hh2, hh3, mapping, lw, lb, fout, G);
}